// Round 9
// baseline (160.515 us; speedup 1.0000x reference)
//
#include <hip/hip_runtime.h>
#include <cfloat>
#include <cmath>

#define HW 25600      // 160*160
#define WIDTH 160
#define NB 4
#define NC 128

typedef float f32x2 __attribute__((ext_vector_type(2)));
typedef float f32x4 __attribute__((ext_vector_type(4)));

__device__ __forceinline__ float gelu_exact(float x) {
    return 0.5f * x * (1.f + erff(x * 0.70710678118654752f));
}
__device__ __forceinline__ float sigmoidf_(float x) {
    return 1.f / (1.f + expf(-x));
}
// Packed fp32 FMA: lowers to v_pk_fma_f32 if gfx950 has it, else 2x v_fma_f32.
// Correct either way (R6/R7 lesson: never hand-emit an opcode clang won't name).
__device__ __forceinline__ f32x2 fma2_(f32x2 a, f32x2 b, f32x2 c) {
    return __builtin_elementwise_fma(a, b, c);
}

// ---------------- K0: pack conv weights -> f32x2 (ic0,ic1), per g: [ky][oc][kx] ----------------
__global__ __launch_bounds__(256) void pack_w_kernel(const float* __restrict__ dww,
                                                     f32x2* __restrict__ wpk) {
    int i = blockIdx.x * 256 + threadIdx.x;  // 128*98 = 12544
    if (i >= 128 * 98) return;
    int g = i / 98; int r = i - g * 98;
    int ky = r / 14; int r2 = r - ky * 14;
    int oc = r2 / 7; int kx = r2 - oc * 7;
    int o = 2 * g + oc;
    f32x2 w;
    w.x = dww[(o * 2 + 0) * 49 + ky * 7 + kx];
    w.y = dww[(o * 2 + 1) * 49 + ky * 7 + kx];
    wpk[i] = w;
}

// ---------------- K1: per-plane means (tau*512 + b*128 + c) ----------------
__global__ __launch_bounds__(256) void mean_kernel(const float* __restrict__ RGB,
                                                   const float* __restrict__ T,
                                                   float* __restrict__ means) {
    int p = blockIdx.x;  // 0..1023
    const float* src = (p < 512) ? (RGB + (size_t)p * HW)
                                 : (T + (size_t)(p - 512) * HW);
    const float4* s4 = (const float4*)src;
    float s = 0.f;
    for (int i = threadIdx.x; i < HW / 4; i += 256) {
        float4 v = s4[i];
        s += (v.x + v.y) + (v.z + v.w);
    }
    for (int off = 32; off; off >>= 1) s += __shfl_down(s, off);
    __shared__ float r[4];
    if ((threadIdx.x & 63) == 0) r[threadIdx.x >> 6] = s;
    __syncthreads();
    if (threadIdx.x == 0) means[p] = (r[0] + r[1] + r[2] + r[3]) * (1.f / (float)HW);
}

// ---------------- K2: feature-pool MLP + L2-normalize, per (tau,b) ----------------
__global__ __launch_bounds__(256) void mlp_kernel(const float* __restrict__ means,
                                                  const float* __restrict__ dww,
                                                  const float* __restrict__ dwb,
                                                  const float* __restrict__ uww,
                                                  const float* __restrict__ uwb,
                                                  float* __restrict__ ynorm) {
    int tb = blockIdx.x;  // tau*4 + b
    int t = threadIdx.x;
    __shared__ float sm[128];
    __shared__ float sh[256];
    __shared__ float zz[256];
    __shared__ float r4[4];
    if (t < 128) sm[t] = means[tb * 128 + t];
    __syncthreads();
    float a = dwb[t];
    const float* wrow = dww + t * 128;
    for (int c = 0; c < 128; ++c) a += wrow[c] * sm[c];
    sh[t] = gelu_exact(a);
    __syncthreads();
    int c = t & 127, half = t >> 7;
    float z = 0.f;
    const float* urow = uww + c * 256 + half * 128;
    const float* hh = sh + half * 128;
    for (int j = 0; j < 128; ++j) z += urow[j] * hh[j];
    zz[t] = z;
    __syncthreads();
    float y = 0.f;
    if (t < 128) y = zz[t] + zz[t + 128] + uwb[t];
    float p = y * y;
    for (int off = 32; off; off >>= 1) p += __shfl_down(p, off);
    if ((t & 63) == 0) r4[t >> 6] = p;
    __syncthreads();
    float nrm = sqrtf(r4[0] + r4[1] + r4[2] + r4[3]);
    if (t < 128) ynorm[tb * 128 + t] = y / nrm;
}

// ---------------- K3: gated grouped 7x7 conv + spatial max, packed fp32 ----------------
// Tile element = float2{ch0,ch1}: packing dim is the channel, sliding happens
// across elements, so every packed operand is a naturally aligned pair.
#define TW2 166
#define THR 22
#define NYT 10
__global__ __launch_bounds__(256, 4) void conv_max_kernel(const float* __restrict__ RGB,
                                                          const float* __restrict__ T,
                                                          const f32x2* __restrict__ wpk,
                                                          const float* __restrict__ ynorm,
                                                          float* __restrict__ part) {
    int yt = blockIdx.x;  // 0..9
    int g  = blockIdx.y;  // 0..127
    int b  = blockIdx.z;  // 0..3
    int t  = threadIdx.x;
    __shared__ f32x2 tile[THR * TW2];   // 29.7 KB
    __shared__ float r0s[4], r1s[4];
    int ic0 = 2 * g;
    int c0 = ic0 & 127, c1 = (ic0 + 1) & 127;
    const float* base = (ic0 < 128) ? RGB : T;
    const float* plane0 = base + ((size_t)(b * 128 + c0)) * HW;
    const float* plane1 = base + ((size_t)(b * 128 + c1)) * HW;
    int i0 = b * 128 + c0, i1 = b * 128 + c1;
    int j0 = i0 & 3, k0 = i0 >> 2, j1 = i1 & 3, k1 = i1 >> 2;
    float gate0 = sigmoidf_(128.f * ynorm[j0 * 128 + j0] * ynorm[512 + j0 * 128 + k0]);
    float gate1 = sigmoidf_(128.f * ynorm[j1 * 128 + j1] * ynorm[512 + j1 * 128 + k1]);
    // stage gated, zero-padded, channel-interleaved f32 tile
    int y0 = yt * 16 - 3;
    for (int e = t; e < THR * TW2; e += 256) {
        int row = e / TW2;
        int col = e - row * TW2;
        int gy = y0 + row, gx = col - 3;
        f32x2 v; v.x = 0.f; v.y = 0.f;
        if (gy >= 0 && gy < 160 && gx >= 0 && gx < 160) {
            int off = gy * WIDTH + gx;
            v.x = plane0[off] * gate0;
            v.y = plane1[off] * gate1;
        }
        tile[e] = v;
    }
    __syncthreads();
    int xs = (t & 15) * 10;
    int ys = t >> 4;            // 0..15
    f32x2 z; z.x = 0.f; z.y = 0.f;
    f32x2 A0 = z, A1 = z, A2 = z, A3 = z, A4 = z;
    f32x2 A5 = z, A6 = z, A7 = z, A8 = z, A9 = z;
    f32x2 B0 = z, B1 = z, B2 = z, B3 = z, B4 = z;
    f32x2 B5 = z, B6 = z, B7 = z, B8 = z, B9 = z;
    const f32x2* wgp = wpk + g * 98;   // block-uniform -> scalar loads
    #pragma unroll 1
    for (int ky = 0; ky < 7; ++ky) {
        f32x2 wk[14];
        #pragma unroll
        for (int j = 0; j < 14; ++j) wk[j] = wgp[ky * 14 + j];
        const f32x2* trow = tile + (ys + ky) * TW2 + xs;
        f32x2 win[16];
        #pragma unroll
        for (int j = 0; j < 16; ++j) win[j] = trow[j];
        #pragma unroll
        for (int kx = 0; kx < 7; ++kx) {
            f32x2 w0 = wk[kx];
            f32x2 w1 = wk[7 + kx];
            A0 = fma2_(w0, win[kx + 0], A0); B0 = fma2_(w1, win[kx + 0], B0);
            A1 = fma2_(w0, win[kx + 1], A1); B1 = fma2_(w1, win[kx + 1], B1);
            A2 = fma2_(w0, win[kx + 2], A2); B2 = fma2_(w1, win[kx + 2], B2);
            A3 = fma2_(w0, win[kx + 3], A3); B3 = fma2_(w1, win[kx + 3], B3);
            A4 = fma2_(w0, win[kx + 4], A4); B4 = fma2_(w1, win[kx + 4], B4);
            A5 = fma2_(w0, win[kx + 5], A5); B5 = fma2_(w1, win[kx + 5], B5);
            A6 = fma2_(w0, win[kx + 6], A6); B6 = fma2_(w1, win[kx + 6], B6);
            A7 = fma2_(w0, win[kx + 7], A7); B7 = fma2_(w1, win[kx + 7], B7);
            A8 = fma2_(w0, win[kx + 8], A8); B8 = fma2_(w1, win[kx + 8], B8);
            A9 = fma2_(w0, win[kx + 9], A9); B9 = fma2_(w1, win[kx + 9], B9);
        }
    }
    float m0 = fmaxf(fmaxf(fmaxf(A0.x + A0.y, A1.x + A1.y), fmaxf(A2.x + A2.y, A3.x + A3.y)),
                     fmaxf(fmaxf(A4.x + A4.y, A5.x + A5.y),
                           fmaxf(fmaxf(A6.x + A6.y, A7.x + A7.y), fmaxf(A8.x + A8.y, A9.x + A9.y))));
    float m1 = fmaxf(fmaxf(fmaxf(B0.x + B0.y, B1.x + B1.y), fmaxf(B2.x + B2.y, B3.x + B3.y)),
                     fmaxf(fmaxf(B4.x + B4.y, B5.x + B5.y),
                           fmaxf(fmaxf(B6.x + B6.y, B7.x + B7.y), fmaxf(B8.x + B8.y, B9.x + B9.y))));
    for (int off = 32; off; off >>= 1) {
        m0 = fmaxf(m0, __shfl_down(m0, off));
        m1 = fmaxf(m1, __shfl_down(m1, off));
    }
    if ((t & 63) == 0) { r0s[t >> 6] = m0; r1s[t >> 6] = m1; }
    __syncthreads();
    if (t == 0) {
        m0 = fmaxf(fmaxf(r0s[0], r0s[1]), fmaxf(r0s[2], r0s[3]));
        m1 = fmaxf(fmaxf(r1s[0], r1s[1]), fmaxf(r1s[2], r1s[3]));
        int bb = ((b * 128 + g) * NYT + yt) * 2;
        part[bb] = m0;
        part[bb + 1] = m1;
    }
}

// ---------------- K4: max-reduce + channel-att MLP -> per-channel coefficients ----------------
__global__ __launch_bounds__(256) void att_kernel(const float* __restrict__ ynorm,
                                                  const float* __restrict__ part,
                                                  const float* __restrict__ dwb,
                                                  const float* __restrict__ cdw,
                                                  const float* __restrict__ cdb,
                                                  const float* __restrict__ cuw,
                                                  const float* __restrict__ cub,
                                                  const float* __restrict__ srw,
                                                  const float* __restrict__ stw,
                                                  float* __restrict__ coefs) {
    int t = threadIdx.x;
    __shared__ float scg[512];
    __shared__ float smax[1024];
    __shared__ float sh2[64];
    __shared__ float sfg[1024];
    for (int idx = t; idx < 512; idx += 256) {
        int kk = idx >> 2, j = idx & 3;
        scg[idx] = sigmoidf_(128.f * ynorm[j * 128 + j] * ynorm[512 + j * 128 + kk]);
    }
    for (int idx = t; idx < 1024; idx += 256) {
        int b = idx >> 8, o = idx & 255;
        int gg = o >> 1, oc = o & 1;
        const float* pp = part + ((b * 128 + gg) * NYT) * 2 + oc;
        float m = pp[0];
        #pragma unroll
        for (int yt = 1; yt < NYT; ++yt) m = fmaxf(m, pp[yt * 2]);
        smax[idx] = m + dwb[o];
    }
    __syncthreads();
    if (t < 64) {
        int b = t >> 4, j = t & 15;
        float a = cdb[j];
        const float* wrow = cdw + j * 256;
        const float* mx = smax + b * 256;
        for (int o = 0; o < 256; ++o) a += wrow[o] * mx[o];
        sh2[t] = gelu_exact(a);
    }
    __syncthreads();
    for (int idx = t; idx < 1024; idx += 256) {
        int b = idx >> 8, o = idx & 255;
        float z = cub[o];
        const float* ur = cuw + o * 16;
        const float* hh = sh2 + b * 16;
        #pragma unroll
        for (int j = 0; j < 16; ++j) z += ur[j] * hh[j];
        sfg[idx] = sigmoidf_(z);
    }
    __syncthreads();
    for (int idx = t; idx < 512; idx += 256) {
        int b = idx >> 7, c = idx & 127;
        float cgv = scg[idx];
        float ar = cgv * sfg[b * 256 + c] + 1.f - cgv;
        float at = cgv * sfg[b * 256 + 128 + c] + 1.f - cgv;
        coefs[idx] = ar;
        coefs[512 + idx] = at;
        coefs[1024 + idx] = ar * srw[c];
        coefs[1536 + idx] = at * stw[c];
    }
}

// ---------------- K5: spatial-att fuse + final outputs (R8-proven two-pass, NT stores) ----------------
__global__ __launch_bounds__(256) void fuse_kernel(const float* __restrict__ RGB,
                                                   const float* __restrict__ T,
                                                   const float* __restrict__ coefs,
                                                   const float* __restrict__ srb,
                                                   const float* __restrict__ stb,
                                                   float* __restrict__ out) {
    int b = blockIdx.y;
    int t = threadIdx.x;
    int w = t >> 6, lane = t & 63;
    int pix = blockIdx.x * 256 + lane * 4;
    __shared__ float sco[4][128];
    for (int i = t; i < 512; i += 256) {
        int a = i >> 7, c = i & 127;
        sco[a][c] = coefs[a * 512 + b * 128 + c];
    }
    __syncthreads();
    const float* rp = RGB + (size_t)b * NC * HW;
    const float* tp = T + (size_t)b * NC * HW;
    float4 df = make_float4(0.f, 0.f, 0.f, 0.f);
    for (int ci = 0; ci < 32; ++ci) {
        int c = w + ci * 4;
        size_t off = (size_t)c * HW + pix;
        float4 r = *(const float4*)(rp + off);
        float4 tv = *(const float4*)(tp + off);
        float wrc = sco[2][c], wtc = sco[3][c];
        df.x += r.x * wrc - tv.x * wtc;
        df.y += r.y * wrc - tv.y * wtc;
        df.z += r.z * wrc - tv.z * wtc;
        df.w += r.w * wrc - tv.w * wtc;
    }
    __shared__ float4 sdf[4][64];
    sdf[w][lane] = df;
    __syncthreads();
    float4 d0 = sdf[0][lane], d1 = sdf[1][lane], d2 = sdf[2][lane], d3 = sdf[3][lane];
    float bias = srb[0] - stb[0];
    float ax = sigmoidf_(d0.x + d1.x + d2.x + d3.x + bias);
    float ay = sigmoidf_(d0.y + d1.y + d2.y + d3.y + bias);
    float az = sigmoidf_(d0.z + d1.z + d2.z + d3.z + bias);
    float aw = sigmoidf_(d0.w + d1.w + d2.w + d3.w + bias);
    float* outR = out + (size_t)b * NC * HW;
    float* outT = out + (size_t)NB * NC * HW + (size_t)b * NC * HW;
    for (int ci = 0; ci < 32; ++ci) {
        int c = w + ci * 4;
        size_t off = (size_t)c * HW + pix;
        float4 r = *(const float4*)(rp + off);
        float4 tv = *(const float4*)(tp + off);
        float arc = sco[0][c], atc = sco[1][c];
        f32x4 o1, o2;
        o1.x = r.x * arc * ax;  o2.x = tv.x * atc * (1.f - ax);
        o1.y = r.y * arc * ay;  o2.y = tv.y * atc * (1.f - ay);
        o1.z = r.z * arc * az;  o2.z = tv.z * atc * (1.f - az);
        o1.w = r.w * arc * aw;  o2.w = tv.w * atc * (1.f - aw);
        __builtin_nontemporal_store(o1, (f32x4*)(outR + off));
        __builtin_nontemporal_store(o2, (f32x4*)(outT + off));
    }
}

extern "C" void kernel_launch(void* const* d_in, const int* in_sizes, int n_in,
                              void* d_out, int out_size, void* d_ws, size_t ws_size,
                              hipStream_t stream) {
    const float* RGB       = (const float*)d_in[0];
    const float* T         = (const float*)d_in[1];
    const float* fp_down_w = (const float*)d_in[2];
    const float* fp_down_b = (const float*)d_in[3];
    const float* fp_up_w   = (const float*)d_in[4];
    const float* fp_up_b   = (const float*)d_in[5];
    const float* dw_w      = (const float*)d_in[6];
    const float* dw_b      = (const float*)d_in[7];
    const float* ca_down_w = (const float*)d_in[8];
    const float* ca_down_b = (const float*)d_in[9];
    const float* ca_up_w   = (const float*)d_in[10];
    const float* ca_up_b   = (const float*)d_in[11];
    const float* sr_w      = (const float*)d_in[12];
    const float* sr_b      = (const float*)d_in[13];
    const float* st_w      = (const float*)d_in[14];
    const float* st_b      = (const float*)d_in[15];
    float* out = (float*)d_out;
    float* ws  = (float*)d_ws;

    // ws float layout:
    //   [0,1024)        means (tau*512 + b*128 + c)
    //   [1024,2048)     ynorm
    //   [2048,12288)    conv partial maxes: ((b*128+g)*10+yt)*2 + oc
    //   [12288,14336)   coefs: alpha_r | alpha_t | wr | wt  (each 512)
    //   [14336,39424)   wpk: packed f32x2 conv weights [g][ky][oc][kx]  (~154KB total ws)
    f32x2* wpk = (f32x2*)(ws + 14336);
    pack_w_kernel<<<49, 256, 0, stream>>>(dw_w, wpk);
    mean_kernel<<<1024, 256, 0, stream>>>(RGB, T, ws);
    mlp_kernel<<<8, 256, 0, stream>>>(ws, fp_down_w, fp_down_b, fp_up_w, fp_up_b, ws + 1024);
    conv_max_kernel<<<dim3(NYT, 128, 4), 256, 0, stream>>>(RGB, T, wpk, ws + 1024, ws + 2048);
    att_kernel<<<1, 256, 0, stream>>>(ws + 1024, ws + 2048, dw_b, ca_down_w, ca_down_b,
                                      ca_up_w, ca_up_b, sr_w, st_w, ws + 12288);
    fuse_kernel<<<dim3(100, 4), 256, 0, stream>>>(RGB, T, ws + 12288, sr_b, st_b, out);
}

// Round 10
// 150.424 us; speedup vs baseline: 1.0671x; 1.0671x over previous
//
#include <hip/hip_runtime.h>
#include <hip/hip_fp16.h>
#include <cfloat>
#include <cmath>

#define HW 25600      // 160*160
#define WIDTH 160
#define NB 4
#define NC 128

typedef float f32x4 __attribute__((ext_vector_type(4)));

__device__ __forceinline__ float gelu_exact(float x) {
    return 0.5f * x * (1.f + erff(x * 0.70710678118654752f));
}
__device__ __forceinline__ float sigmoidf_(float x) {
    return 1.f / (1.f + expf(-x));
}

__device__ __forceinline__ unsigned pack_pkrtz(float a, float b) {
    return __builtin_bit_cast(unsigned, __builtin_amdgcn_cvt_pkrtz(a, b));
}
__device__ __forceinline__ __half2 u2h(unsigned u) {
    return __builtin_bit_cast(__half2, u);
}
__device__ __forceinline__ float h2sum(__half2 h) {
    return __half2float(__low2half(h)) + __half2float(__high2half(h));
}

// ---------------- K0: pack conv weights -> f16x2 (ic0,ic1), per g: [ky][oc][kx] ----------------
__global__ __launch_bounds__(256) void pack_w_kernel(const float* __restrict__ dww,
                                                     unsigned* __restrict__ wpk) {
    int i = blockIdx.x * 256 + threadIdx.x;  // 128*98 = 12544
    if (i >= 128 * 98) return;
    int g = i / 98; int r = i - g * 98;
    int ky = r / 14; int r2 = r - ky * 14;
    int oc = r2 / 7; int kx = r2 - oc * 7;
    int o = 2 * g + oc;
    float wa = dww[(o * 2 + 0) * 49 + ky * 7 + kx];
    float wb = dww[(o * 2 + 1) * 49 + ky * 7 + kx];
    wpk[i] = pack_pkrtz(wa, wb);
}

// ---------------- K1: per-plane means (tau*512 + b*128 + c) ----------------
__global__ __launch_bounds__(256) void mean_kernel(const float* __restrict__ RGB,
                                                   const float* __restrict__ T,
                                                   float* __restrict__ means) {
    int p = blockIdx.x;  // 0..1023
    const float* src = (p < 512) ? (RGB + (size_t)p * HW)
                                 : (T + (size_t)(p - 512) * HW);
    const float4* s4 = (const float4*)src;
    float s = 0.f;
    for (int i = threadIdx.x; i < HW / 4; i += 256) {
        float4 v = s4[i];
        s += (v.x + v.y) + (v.z + v.w);
    }
    for (int off = 32; off; off >>= 1) s += __shfl_down(s, off);
    __shared__ float r[4];
    if ((threadIdx.x & 63) == 0) r[threadIdx.x >> 6] = s;
    __syncthreads();
    if (threadIdx.x == 0) means[p] = (r[0] + r[1] + r[2] + r[3]) * (1.f / (float)HW);
}

// ---------------- K2: feature-pool MLP + L2-normalize, per (tau,b) ----------------
__global__ __launch_bounds__(256) void mlp_kernel(const float* __restrict__ means,
                                                  const float* __restrict__ dww,
                                                  const float* __restrict__ dwb,
                                                  const float* __restrict__ uww,
                                                  const float* __restrict__ uwb,
                                                  float* __restrict__ ynorm) {
    int tb = blockIdx.x;  // tau*4 + b
    int t = threadIdx.x;
    __shared__ float sm[128];
    __shared__ float sh[256];
    __shared__ float zz[256];
    __shared__ float r4[4];
    if (t < 128) sm[t] = means[tb * 128 + t];
    __syncthreads();
    float a = dwb[t];
    const float* wrow = dww + t * 128;
    for (int c = 0; c < 128; ++c) a += wrow[c] * sm[c];
    sh[t] = gelu_exact(a);
    __syncthreads();
    int c = t & 127, half = t >> 7;
    float z = 0.f;
    const float* urow = uww + c * 256 + half * 128;
    const float* hh = sh + half * 128;
    for (int j = 0; j < 128; ++j) z += urow[j] * hh[j];
    zz[t] = z;
    __syncthreads();
    float y = 0.f;
    if (t < 128) y = zz[t] + zz[t + 128] + uwb[t];
    float p = y * y;
    for (int off = 32; off; off >>= 1) p += __shfl_down(p, off);
    if ((t & 63) == 0) r4[t >> 6] = p;
    __syncthreads();
    float nrm = sqrtf(r4[0] + r4[1] + r4[2] + r4[3]);
    if (t < 128) ynorm[tb * 128 + t] = y / nrm;
}

// ---------------- K3: gated grouped 7x7 conv + spatial max (R8-proven, 67.9us anchor) ----------------
#define TW2 166
#define THR 22
#define NYT 10
__global__ __launch_bounds__(256, 4) void conv_max_kernel(const float* __restrict__ RGB,
                                                          const float* __restrict__ T,
                                                          const unsigned* __restrict__ wpk,
                                                          const float* __restrict__ ynorm,
                                                          float* __restrict__ part) {
    int yt = blockIdx.x;  // 0..9
    int g  = blockIdx.y;  // 0..127
    int b  = blockIdx.z;  // 0..3
    int t  = threadIdx.x;
    __shared__ unsigned tile[THR * TW2];   // 14.6 KB
    __shared__ float r0s[4], r1s[4];
    int ic0 = 2 * g;
    int c0 = ic0 & 127, c1 = (ic0 + 1) & 127;
    const float* base = (ic0 < 128) ? RGB : T;
    const float* plane0 = base + ((size_t)(b * 128 + c0)) * HW;
    const float* plane1 = base + ((size_t)(b * 128 + c1)) * HW;
    int i0 = b * 128 + c0, i1 = b * 128 + c1;
    int j0 = i0 & 3, k0 = i0 >> 2, j1 = i1 & 3, k1 = i1 >> 2;
    float gate0 = sigmoidf_(128.f * ynorm[j0 * 128 + j0] * ynorm[512 + j0 * 128 + k0]);
    float gate1 = sigmoidf_(128.f * ynorm[j1 * 128 + j1] * ynorm[512 + j1 * 128 + k1]);
    int y0 = yt * 16 - 3;
    for (int e = t; e < THR * TW2; e += 256) {
        int row = e / TW2;
        int col = e - row * TW2;
        int gy = y0 + row, gx = col - 3;
        float v0 = 0.f, v1 = 0.f;
        if (gy >= 0 && gy < 160 && gx >= 0 && gx < 160) {
            int off = gy * WIDTH + gx;
            v0 = plane0[off] * gate0;
            v1 = plane1[off] * gate1;
        }
        tile[e] = pack_pkrtz(v0, v1);
    }
    __syncthreads();
    int xs = (t & 15) * 10;     // 40 B aligned -> uint2 ok
    int ys = t >> 4;            // 0..15
    __half2 A0 = u2h(0u), A1 = u2h(0u), A2 = u2h(0u), A3 = u2h(0u), A4 = u2h(0u);
    __half2 A5 = u2h(0u), A6 = u2h(0u), A7 = u2h(0u), A8 = u2h(0u), A9 = u2h(0u);
    __half2 B0 = u2h(0u), B1 = u2h(0u), B2 = u2h(0u), B3 = u2h(0u), B4 = u2h(0u);
    __half2 B5 = u2h(0u), B6 = u2h(0u), B7 = u2h(0u), B8 = u2h(0u), B9 = u2h(0u);
    const unsigned* wgp = wpk + g * 98;   // block-uniform -> scalar loads
    #pragma unroll 1
    for (int ky = 0; ky < 7; ++ky) {
        unsigned wk[14];
        #pragma unroll
        for (int j = 0; j < 14; ++j) wk[j] = wgp[ky * 14 + j];
        const uint2* tr2 = (const uint2*)(tile + (ys + ky) * TW2 + xs);
        unsigned win[16];
        #pragma unroll
        for (int j = 0; j < 8; ++j) {
            uint2 p = tr2[j];
            win[2 * j] = p.x;
            win[2 * j + 1] = p.y;
        }
        #pragma unroll
        for (int kx = 0; kx < 7; ++kx) {
            __half2 w0 = u2h(wk[kx]);
            __half2 w1 = u2h(wk[7 + kx]);
            __half2 v;
            v = u2h(win[kx + 0]); A0 = __hfma2(w0, v, A0); B0 = __hfma2(w1, v, B0);
            v = u2h(win[kx + 1]); A1 = __hfma2(w0, v, A1); B1 = __hfma2(w1, v, B1);
            v = u2h(win[kx + 2]); A2 = __hfma2(w0, v, A2); B2 = __hfma2(w1, v, B2);
            v = u2h(win[kx + 3]); A3 = __hfma2(w0, v, A3); B3 = __hfma2(w1, v, B3);
            v = u2h(win[kx + 4]); A4 = __hfma2(w0, v, A4); B4 = __hfma2(w1, v, B4);
            v = u2h(win[kx + 5]); A5 = __hfma2(w0, v, A5); B5 = __hfma2(w1, v, B5);
            v = u2h(win[kx + 6]); A6 = __hfma2(w0, v, A6); B6 = __hfma2(w1, v, B6);
            v = u2h(win[kx + 7]); A7 = __hfma2(w0, v, A7); B7 = __hfma2(w1, v, B7);
            v = u2h(win[kx + 8]); A8 = __hfma2(w0, v, A8); B8 = __hfma2(w1, v, B8);
            v = u2h(win[kx + 9]); A9 = __hfma2(w0, v, A9); B9 = __hfma2(w1, v, B9);
        }
    }
    float m0 = fmaxf(fmaxf(fmaxf(h2sum(A0), h2sum(A1)), fmaxf(h2sum(A2), h2sum(A3))),
                     fmaxf(fmaxf(h2sum(A4), h2sum(A5)),
                           fmaxf(fmaxf(h2sum(A6), h2sum(A7)), fmaxf(h2sum(A8), h2sum(A9)))));
    float m1 = fmaxf(fmaxf(fmaxf(h2sum(B0), h2sum(B1)), fmaxf(h2sum(B2), h2sum(B3))),
                     fmaxf(fmaxf(h2sum(B4), h2sum(B5)),
                           fmaxf(fmaxf(h2sum(B6), h2sum(B7)), fmaxf(h2sum(B8), h2sum(B9)))));
    for (int off = 32; off; off >>= 1) {
        m0 = fmaxf(m0, __shfl_down(m0, off));
        m1 = fmaxf(m1, __shfl_down(m1, off));
    }
    if ((t & 63) == 0) { r0s[t >> 6] = m0; r1s[t >> 6] = m1; }
    __syncthreads();
    if (t == 0) {
        m0 = fmaxf(fmaxf(r0s[0], r0s[1]), fmaxf(r0s[2], r0s[3]));
        m1 = fmaxf(fmaxf(r1s[0], r1s[1]), fmaxf(r1s[2], r1s[3]));
        int bb = ((b * 128 + g) * NYT + yt) * 2;
        part[bb] = m0;
        part[bb + 1] = m1;
    }
}

// ---------------- K4: max-reduce + channel-att MLP -> per-channel coefficients ----------------
__global__ __launch_bounds__(256) void att_kernel(const float* __restrict__ ynorm,
                                                  const float* __restrict__ part,
                                                  const float* __restrict__ dwb,
                                                  const float* __restrict__ cdw,
                                                  const float* __restrict__ cdb,
                                                  const float* __restrict__ cuw,
                                                  const float* __restrict__ cub,
                                                  const float* __restrict__ srw,
                                                  const float* __restrict__ stw,
                                                  float* __restrict__ coefs) {
    int t = threadIdx.x;
    __shared__ float scg[512];
    __shared__ float smax[1024];
    __shared__ float sh2[64];
    __shared__ float sfg[1024];
    for (int idx = t; idx < 512; idx += 256) {
        int kk = idx >> 2, j = idx & 3;
        scg[idx] = sigmoidf_(128.f * ynorm[j * 128 + j] * ynorm[512 + j * 128 + kk]);
    }
    for (int idx = t; idx < 1024; idx += 256) {
        int b = idx >> 8, o = idx & 255;
        int gg = o >> 1, oc = o & 1;
        const float* pp = part + ((b * 128 + gg) * NYT) * 2 + oc;
        float m = pp[0];
        #pragma unroll
        for (int yt = 1; yt < NYT; ++yt) m = fmaxf(m, pp[yt * 2]);
        smax[idx] = m + dwb[o];
    }
    __syncthreads();
    if (t < 64) {
        int b = t >> 4, j = t & 15;
        float a = cdb[j];
        const float* wrow = cdw + j * 256;
        const float* mx = smax + b * 256;
        for (int o = 0; o < 256; ++o) a += wrow[o] * mx[o];
        sh2[t] = gelu_exact(a);
    }
    __syncthreads();
    for (int idx = t; idx < 1024; idx += 256) {
        int b = idx >> 8, o = idx & 255;
        float z = cub[o];
        const float* ur = cuw + o * 16;
        const float* hh = sh2 + b * 16;
        #pragma unroll
        for (int j = 0; j < 16; ++j) z += ur[j] * hh[j];
        sfg[idx] = sigmoidf_(z);
    }
    __syncthreads();
    for (int idx = t; idx < 512; idx += 256) {
        int b = idx >> 7, c = idx & 127;
        float cgv = scg[idx];
        float ar = cgv * sfg[b * 256 + c] + 1.f - cgv;
        float at = cgv * sfg[b * 256 + 128 + c] + 1.f - cgv;
        coefs[idx] = ar;
        coefs[512 + idx] = at;
        coefs[1024 + idx] = ar * srw[c];
        coefs[1536 + idx] = at * stw[c];
    }
}

// ---------------- K5: spatial-att fuse, SINGLE read pass (values held in regs) ----------------
// 64 px per block, 1 px/thread, warp w owns channels w*32..w*32+31.
// Sole change vs passing R8 (isolates the R6/R7 untested suspect).
__global__ __launch_bounds__(256, 4) void fuse_kernel(const float* __restrict__ RGB,
                                                      const float* __restrict__ T,
                                                      const float* __restrict__ coefs,
                                                      const float* __restrict__ srb,
                                                      const float* __restrict__ stb,
                                                      float* __restrict__ out) {
    int b = blockIdx.y;
    int t = threadIdx.x;
    int w = t >> 6, lane = t & 63;
    int pix = blockIdx.x * 64 + lane;
    __shared__ float sco[4][128];
    for (int i = t; i < 512; i += 256) {
        int a = i >> 7, c = i & 127;
        sco[a][c] = coefs[a * 512 + b * 128 + c];
    }
    __syncthreads();
    const float* rp = RGB + (size_t)b * NC * HW;
    const float* tp = T + (size_t)b * NC * HW;
    float rv[32], tv[32];
    float df = 0.f;
    #pragma unroll
    for (int ci = 0; ci < 32; ++ci) {
        int c = w * 32 + ci;
        size_t off = (size_t)c * HW + pix;
        rv[ci] = rp[off];
        tv[ci] = tp[off];
        df += rv[ci] * sco[2][c] - tv[ci] * sco[3][c];
    }
    __shared__ float sdf[4][64];
    sdf[w][lane] = df;
    __syncthreads();
    float a = sigmoidf_(sdf[0][lane] + sdf[1][lane] + sdf[2][lane] + sdf[3][lane]
                        + srb[0] - stb[0]);
    float na = 1.f - a;
    float* outR = out + (size_t)b * NC * HW;
    float* outT = out + (size_t)NB * NC * HW + (size_t)b * NC * HW;
    #pragma unroll
    for (int ci = 0; ci < 32; ++ci) {
        int c = w * 32 + ci;
        size_t off = (size_t)c * HW + pix;
        __builtin_nontemporal_store(rv[ci] * sco[0][c] * a, outR + off);
        __builtin_nontemporal_store(tv[ci] * sco[1][c] * na, outT + off);
    }
}

extern "C" void kernel_launch(void* const* d_in, const int* in_sizes, int n_in,
                              void* d_out, int out_size, void* d_ws, size_t ws_size,
                              hipStream_t stream) {
    const float* RGB       = (const float*)d_in[0];
    const float* T         = (const float*)d_in[1];
    const float* fp_down_w = (const float*)d_in[2];
    const float* fp_down_b = (const float*)d_in[3];
    const float* fp_up_w   = (const float*)d_in[4];
    const float* fp_up_b   = (const float*)d_in[5];
    const float* dw_w      = (const float*)d_in[6];
    const float* dw_b      = (const float*)d_in[7];
    const float* ca_down_w = (const float*)d_in[8];
    const float* ca_down_b = (const float*)d_in[9];
    const float* ca_up_w   = (const float*)d_in[10];
    const float* ca_up_b   = (const float*)d_in[11];
    const float* sr_w      = (const float*)d_in[12];
    const float* sr_b      = (const float*)d_in[13];
    const float* st_w      = (const float*)d_in[14];
    const float* st_b      = (const float*)d_in[15];
    float* out = (float*)d_out;
    float* ws  = (float*)d_ws;

    // ws float layout (R8-proven footprint):
    //   [0,1024)        means (tau*512 + b*128 + c)
    //   [1024,2048)     ynorm
    //   [2048,12288)    conv partial maxes: ((b*128+g)*10+yt)*2 + oc
    //   [12288,14336)   coefs: alpha_r | alpha_t | wr | wt  (each 512)
    //   [14336,26880)   wpk: packed f16x2 conv weights [g][ky][oc][kx]
    unsigned* wpk = (unsigned*)(ws + 14336);
    pack_w_kernel<<<49, 256, 0, stream>>>(dw_w, wpk);
    mean_kernel<<<1024, 256, 0, stream>>>(RGB, T, ws);
    mlp_kernel<<<8, 256, 0, stream>>>(ws, fp_down_w, fp_down_b, fp_up_w, fp_up_b, ws + 1024);
    conv_max_kernel<<<dim3(NYT, 128, 4), 256, 0, stream>>>(RGB, T, wpk, ws + 1024, ws + 2048);
    att_kernel<<<1, 256, 0, stream>>>(ws + 1024, ws + 2048, dw_b, ca_down_w, ca_down_b,
                                      ca_up_w, ca_up_b, sr_w, st_w, ws + 12288);
    fuse_kernel<<<dim3(400, 4), 256, 0, stream>>>(RGB, T, ws + 12288, sr_b, st_b, out);
}

// Round 11
// 140.658 us; speedup vs baseline: 1.1412x; 1.0694x over previous
//
#include <hip/hip_runtime.h>
#include <hip/hip_fp16.h>
#include <cfloat>
#include <cmath>

#define HW 25600      // 160*160
#define WIDTH 160
#define NB 4
#define NC 128

typedef float f32x2 __attribute__((ext_vector_type(2)));

__device__ __forceinline__ float gelu_exact(float x) {
    return 0.5f * x * (1.f + erff(x * 0.70710678118654752f));
}
__device__ __forceinline__ float sigmoidf_(float x) {
    return 1.f / (1.f + expf(-x));
}

__device__ __forceinline__ unsigned pack_pkrtz(float a, float b) {
    return __builtin_bit_cast(unsigned, __builtin_amdgcn_cvt_pkrtz(a, b));
}
__device__ __forceinline__ __half2 u2h(unsigned u) {
    return __builtin_bit_cast(__half2, u);
}
__device__ __forceinline__ float h2sum(__half2 h) {
    return __half2float(__low2half(h)) + __half2float(__high2half(h));
}

// ---------------- K0: pack conv weights -> f16x2 (ic0,ic1), per g: [ky][oc][kx] ----------------
__global__ __launch_bounds__(256) void pack_w_kernel(const float* __restrict__ dww,
                                                     unsigned* __restrict__ wpk) {
    int i = blockIdx.x * 256 + threadIdx.x;  // 128*98 = 12544
    if (i >= 128 * 98) return;
    int g = i / 98; int r = i - g * 98;
    int ky = r / 14; int r2 = r - ky * 14;
    int oc = r2 / 7; int kx = r2 - oc * 7;
    int o = 2 * g + oc;
    float wa = dww[(o * 2 + 0) * 49 + ky * 7 + kx];
    float wb = dww[(o * 2 + 1) * 49 + ky * 7 + kx];
    wpk[i] = pack_pkrtz(wa, wb);
}

// ---------------- K1: per-plane means (tau*512 + b*128 + c) ----------------
__global__ __launch_bounds__(256) void mean_kernel(const float* __restrict__ RGB,
                                                   const float* __restrict__ T,
                                                   float* __restrict__ means) {
    int p = blockIdx.x;  // 0..1023
    const float* src = (p < 512) ? (RGB + (size_t)p * HW)
                                 : (T + (size_t)(p - 512) * HW);
    const float4* s4 = (const float4*)src;
    float s = 0.f;
    for (int i = threadIdx.x; i < HW / 4; i += 256) {
        float4 v = s4[i];
        s += (v.x + v.y) + (v.z + v.w);
    }
    for (int off = 32; off; off >>= 1) s += __shfl_down(s, off);
    __shared__ float r[4];
    if ((threadIdx.x & 63) == 0) r[threadIdx.x >> 6] = s;
    __syncthreads();
    if (threadIdx.x == 0) means[p] = (r[0] + r[1] + r[2] + r[3]) * (1.f / (float)HW);
}

// ---------------- K2: feature-pool MLP + L2-normalize, per (tau,b) ----------------
__global__ __launch_bounds__(256) void mlp_kernel(const float* __restrict__ means,
                                                  const float* __restrict__ dww,
                                                  const float* __restrict__ dwb,
                                                  const float* __restrict__ uww,
                                                  const float* __restrict__ uwb,
                                                  float* __restrict__ ynorm) {
    int tb = blockIdx.x;  // tau*4 + b
    int t = threadIdx.x;
    __shared__ float sm[128];
    __shared__ float sh[256];
    __shared__ float zz[256];
    __shared__ float r4[4];
    if (t < 128) sm[t] = means[tb * 128 + t];
    __syncthreads();
    float a = dwb[t];
    const float* wrow = dww + t * 128;
    for (int c = 0; c < 128; ++c) a += wrow[c] * sm[c];
    sh[t] = gelu_exact(a);
    __syncthreads();
    int c = t & 127, half = t >> 7;
    float z = 0.f;
    const float* urow = uww + c * 256 + half * 128;
    const float* hh = sh + half * 128;
    for (int j = 0; j < 128; ++j) z += urow[j] * hh[j];
    zz[t] = z;
    __syncthreads();
    float y = 0.f;
    if (t < 128) y = zz[t] + zz[t + 128] + uwb[t];
    float p = y * y;
    for (int off = 32; off; off >>= 1) p += __shfl_down(p, off);
    if ((t & 63) == 0) r4[t >> 6] = p;
    __syncthreads();
    float nrm = sqrtf(r4[0] + r4[1] + r4[2] + r4[3]);
    if (t < 128) ynorm[tb * 128 + t] = y / nrm;
}

// ---------------- K3: gated grouped 7x7 conv + spatial max ----------------
// R11 changes vs R8-proven: unroll 2 (pipeline the per-ky s_loads past compute)
// + launch_bounds(256,8) (more resident waves; VGPR cap 64 >> current 20).
#define TW2 166
#define THR 22
#define NYT 10
__global__ __launch_bounds__(256, 8) void conv_max_kernel(const float* __restrict__ RGB,
                                                          const float* __restrict__ T,
                                                          const unsigned* __restrict__ wpk,
                                                          const float* __restrict__ ynorm,
                                                          float* __restrict__ part) {
    int yt = blockIdx.x;  // 0..9
    int g  = blockIdx.y;  // 0..127
    int b  = blockIdx.z;  // 0..3
    int t  = threadIdx.x;
    __shared__ unsigned tile[THR * TW2];   // 14.6 KB
    __shared__ float r0s[4], r1s[4];
    int ic0 = 2 * g;
    int c0 = ic0 & 127, c1 = (ic0 + 1) & 127;
    const float* base = (ic0 < 128) ? RGB : T;
    const float* plane0 = base + ((size_t)(b * 128 + c0)) * HW;
    const float* plane1 = base + ((size_t)(b * 128 + c1)) * HW;
    int i0 = b * 128 + c0, i1 = b * 128 + c1;
    int j0 = i0 & 3, k0 = i0 >> 2, j1 = i1 & 3, k1 = i1 >> 2;
    float gate0 = sigmoidf_(128.f * ynorm[j0 * 128 + j0] * ynorm[512 + j0 * 128 + k0]);
    float gate1 = sigmoidf_(128.f * ynorm[j1 * 128 + j1] * ynorm[512 + j1 * 128 + k1]);
    int y0 = yt * 16 - 3;
    for (int e = t; e < THR * TW2; e += 256) {
        int row = e / TW2;
        int col = e - row * TW2;
        int gy = y0 + row, gx = col - 3;
        float v0 = 0.f, v1 = 0.f;
        if (gy >= 0 && gy < 160 && gx >= 0 && gx < 160) {
            int off = gy * WIDTH + gx;
            v0 = plane0[off] * gate0;
            v1 = plane1[off] * gate1;
        }
        tile[e] = pack_pkrtz(v0, v1);
    }
    __syncthreads();
    int xs = (t & 15) * 10;     // 40 B aligned -> uint2 ok
    int ys = t >> 4;            // 0..15
    __half2 A0 = u2h(0u), A1 = u2h(0u), A2 = u2h(0u), A3 = u2h(0u), A4 = u2h(0u);
    __half2 A5 = u2h(0u), A6 = u2h(0u), A7 = u2h(0u), A8 = u2h(0u), A9 = u2h(0u);
    __half2 B0 = u2h(0u), B1 = u2h(0u), B2 = u2h(0u), B3 = u2h(0u), B4 = u2h(0u);
    __half2 B5 = u2h(0u), B6 = u2h(0u), B7 = u2h(0u), B8 = u2h(0u), B9 = u2h(0u);
    const unsigned* wgp = wpk + g * 98;   // block-uniform -> scalar loads
    #pragma unroll 2
    for (int ky = 0; ky < 7; ++ky) {
        unsigned wk[14];
        #pragma unroll
        for (int j = 0; j < 14; ++j) wk[j] = wgp[ky * 14 + j];
        const uint2* tr2 = (const uint2*)(tile + (ys + ky) * TW2 + xs);
        unsigned win[16];
        #pragma unroll
        for (int j = 0; j < 8; ++j) {
            uint2 p = tr2[j];
            win[2 * j] = p.x;
            win[2 * j + 1] = p.y;
        }
        #pragma unroll
        for (int kx = 0; kx < 7; ++kx) {
            __half2 w0 = u2h(wk[kx]);
            __half2 w1 = u2h(wk[7 + kx]);
            __half2 v;
            v = u2h(win[kx + 0]); A0 = __hfma2(w0, v, A0); B0 = __hfma2(w1, v, B0);
            v = u2h(win[kx + 1]); A1 = __hfma2(w0, v, A1); B1 = __hfma2(w1, v, B1);
            v = u2h(win[kx + 2]); A2 = __hfma2(w0, v, A2); B2 = __hfma2(w1, v, B2);
            v = u2h(win[kx + 3]); A3 = __hfma2(w0, v, A3); B3 = __hfma2(w1, v, B3);
            v = u2h(win[kx + 4]); A4 = __hfma2(w0, v, A4); B4 = __hfma2(w1, v, B4);
            v = u2h(win[kx + 5]); A5 = __hfma2(w0, v, A5); B5 = __hfma2(w1, v, B5);
            v = u2h(win[kx + 6]); A6 = __hfma2(w0, v, A6); B6 = __hfma2(w1, v, B6);
            v = u2h(win[kx + 7]); A7 = __hfma2(w0, v, A7); B7 = __hfma2(w1, v, B7);
            v = u2h(win[kx + 8]); A8 = __hfma2(w0, v, A8); B8 = __hfma2(w1, v, B8);
            v = u2h(win[kx + 9]); A9 = __hfma2(w0, v, A9); B9 = __hfma2(w1, v, B9);
        }
    }
    float m0 = fmaxf(fmaxf(fmaxf(h2sum(A0), h2sum(A1)), fmaxf(h2sum(A2), h2sum(A3))),
                     fmaxf(fmaxf(h2sum(A4), h2sum(A5)),
                           fmaxf(fmaxf(h2sum(A6), h2sum(A7)), fmaxf(h2sum(A8), h2sum(A9)))));
    float m1 = fmaxf(fmaxf(fmaxf(h2sum(B0), h2sum(B1)), fmaxf(h2sum(B2), h2sum(B3))),
                     fmaxf(fmaxf(h2sum(B4), h2sum(B5)),
                           fmaxf(fmaxf(h2sum(B6), h2sum(B7)), fmaxf(h2sum(B8), h2sum(B9)))));
    for (int off = 32; off; off >>= 1) {
        m0 = fmaxf(m0, __shfl_down(m0, off));
        m1 = fmaxf(m1, __shfl_down(m1, off));
    }
    if ((t & 63) == 0) { r0s[t >> 6] = m0; r1s[t >> 6] = m1; }
    __syncthreads();
    if (t == 0) {
        m0 = fmaxf(fmaxf(r0s[0], r0s[1]), fmaxf(r0s[2], r0s[3]));
        m1 = fmaxf(fmaxf(r1s[0], r1s[1]), fmaxf(r1s[2], r1s[3]));
        int bb = ((b * 128 + g) * NYT + yt) * 2;
        part[bb] = m0;
        part[bb + 1] = m1;
    }
}

// ---------------- K4: max-reduce + channel-att MLP -> per-channel coefficients ----------------
__global__ __launch_bounds__(256) void att_kernel(const float* __restrict__ ynorm,
                                                  const float* __restrict__ part,
                                                  const float* __restrict__ dwb,
                                                  const float* __restrict__ cdw,
                                                  const float* __restrict__ cdb,
                                                  const float* __restrict__ cuw,
                                                  const float* __restrict__ cub,
                                                  const float* __restrict__ srw,
                                                  const float* __restrict__ stw,
                                                  float* __restrict__ coefs) {
    int t = threadIdx.x;
    __shared__ float scg[512];
    __shared__ float smax[1024];
    __shared__ float sh2[64];
    __shared__ float sfg[1024];
    for (int idx = t; idx < 512; idx += 256) {
        int kk = idx >> 2, j = idx & 3;
        scg[idx] = sigmoidf_(128.f * ynorm[j * 128 + j] * ynorm[512 + j * 128 + kk]);
    }
    for (int idx = t; idx < 1024; idx += 256) {
        int b = idx >> 8, o = idx & 255;
        int gg = o >> 1, oc = o & 1;
        const float* pp = part + ((b * 128 + gg) * NYT) * 2 + oc;
        float m = pp[0];
        #pragma unroll
        for (int yt = 1; yt < NYT; ++yt) m = fmaxf(m, pp[yt * 2]);
        smax[idx] = m + dwb[o];
    }
    __syncthreads();
    if (t < 64) {
        int b = t >> 4, j = t & 15;
        float a = cdb[j];
        const float* wrow = cdw + j * 256;
        const float* mx = smax + b * 256;
        for (int o = 0; o < 256; ++o) a += wrow[o] * mx[o];
        sh2[t] = gelu_exact(a);
    }
    __syncthreads();
    for (int idx = t; idx < 1024; idx += 256) {
        int b = idx >> 8, o = idx & 255;
        float z = cub[o];
        const float* ur = cuw + o * 16;
        const float* hh = sh2 + b * 16;
        #pragma unroll
        for (int j = 0; j < 16; ++j) z += ur[j] * hh[j];
        sfg[idx] = sigmoidf_(z);
    }
    __syncthreads();
    for (int idx = t; idx < 512; idx += 256) {
        int b = idx >> 7, c = idx & 127;
        float cgv = scg[idx];
        float ar = cgv * sfg[b * 256 + c] + 1.f - cgv;
        float at = cgv * sfg[b * 256 + 128 + c] + 1.f - cgv;
        coefs[idx] = ar;
        coefs[512 + idx] = at;
        coefs[1024 + idx] = ar * srw[c];
        coefs[1536 + idx] = at * stw[c];
    }
}

// ---------------- K5: spatial-att fuse, single pass, float2, 8 warps x 16ch ----------------
// 128 px per block (2 px/thread as float2), warp w owns channels w*16..w*16+15.
__global__ __launch_bounds__(512, 2) void fuse_kernel(const float* __restrict__ RGB,
                                                      const float* __restrict__ T,
                                                      const float* __restrict__ coefs,
                                                      const float* __restrict__ srb,
                                                      const float* __restrict__ stb,
                                                      float* __restrict__ out) {
    int b = blockIdx.y;
    int t = threadIdx.x;
    int w = t >> 6, lane = t & 63;
    int pix = blockIdx.x * 128 + lane * 2;
    __shared__ float sco[4][128];
    for (int i = t; i < 512; i += 512) {
        int a = i >> 7, c = i & 127;
        sco[a][c] = coefs[a * 512 + b * 128 + c];
    }
    { int i = t + 512; if (i < 512 * 1) {} }  // (no-op; single stride covers 512)
    __syncthreads();
    const float* rp = RGB + (size_t)b * NC * HW;
    const float* tp = T + (size_t)b * NC * HW;
    f32x2 rv[16], tv[16];
    f32x2 df; df.x = 0.f; df.y = 0.f;
    #pragma unroll
    for (int ci = 0; ci < 16; ++ci) {
        int c = w * 16 + ci;
        size_t off = (size_t)c * HW + pix;
        rv[ci] = *(const f32x2*)(rp + off);
        tv[ci] = *(const f32x2*)(tp + off);
        float wrc = sco[2][c], wtc = sco[3][c];
        df.x += rv[ci].x * wrc - tv[ci].x * wtc;
        df.y += rv[ci].y * wrc - tv[ci].y * wtc;
    }
    __shared__ f32x2 sdf[8][64];
    sdf[w][lane] = df;
    __syncthreads();
    float sx = srb[0] - stb[0], sy = sx;
    #pragma unroll
    for (int ww = 0; ww < 8; ++ww) {
        f32x2 d = sdf[ww][lane];
        sx += d.x;
        sy += d.y;
    }
    float ax = sigmoidf_(sx), ay = sigmoidf_(sy);
    float* outR = out + (size_t)b * NC * HW;
    float* outT = out + (size_t)NB * NC * HW + (size_t)b * NC * HW;
    #pragma unroll
    for (int ci = 0; ci < 16; ++ci) {
        int c = w * 16 + ci;
        size_t off = (size_t)c * HW + pix;
        float arc = sco[0][c], atc = sco[1][c];
        f32x2 o1, o2;
        o1.x = rv[ci].x * arc * ax;       o1.y = rv[ci].y * arc * ay;
        o2.x = tv[ci].x * atc * (1.f - ax); o2.y = tv[ci].y * atc * (1.f - ay);
        __builtin_nontemporal_store(o1, (f32x2*)(outR + off));
        __builtin_nontemporal_store(o2, (f32x2*)(outT + off));
    }
}

extern "C" void kernel_launch(void* const* d_in, const int* in_sizes, int n_in,
                              void* d_out, int out_size, void* d_ws, size_t ws_size,
                              hipStream_t stream) {
    const float* RGB       = (const float*)d_in[0];
    const float* T         = (const float*)d_in[1];
    const float* fp_down_w = (const float*)d_in[2];
    const float* fp_down_b = (const float*)d_in[3];
    const float* fp_up_w   = (const float*)d_in[4];
    const float* fp_up_b   = (const float*)d_in[5];
    const float* dw_w      = (const float*)d_in[6];
    const float* dw_b      = (const float*)d_in[7];
    const float* ca_down_w = (const float*)d_in[8];
    const float* ca_down_b = (const float*)d_in[9];
    const float* ca_up_w   = (const float*)d_in[10];
    const float* ca_up_b   = (const float*)d_in[11];
    const float* sr_w      = (const float*)d_in[12];
    const float* sr_b      = (const float*)d_in[13];
    const float* st_w      = (const float*)d_in[14];
    const float* st_b      = (const float*)d_in[15];
    float* out = (float*)d_out;
    float* ws  = (float*)d_ws;

    // ws float layout (R8-proven footprint):
    //   [0,1024)        means (tau*512 + b*128 + c)
    //   [1024,2048)     ynorm
    //   [2048,12288)    conv partial maxes: ((b*128+g)*10+yt)*2 + oc
    //   [12288,14336)   coefs: alpha_r | alpha_t | wr | wt  (each 512)
    //   [14336,26880)   wpk: packed f16x2 conv weights [g][ky][oc][kx]
    unsigned* wpk = (unsigned*)(ws + 14336);
    pack_w_kernel<<<49, 256, 0, stream>>>(dw_w, wpk);
    mean_kernel<<<1024, 256, 0, stream>>>(RGB, T, ws);
    mlp_kernel<<<8, 256, 0, stream>>>(ws, fp_down_w, fp_down_b, fp_up_w, fp_up_b, ws + 1024);
    conv_max_kernel<<<dim3(NYT, 128, 4), 256, 0, stream>>>(RGB, T, wpk, ws + 1024, ws + 2048);
    att_kernel<<<1, 256, 0, stream>>>(ws + 1024, ws + 2048, dw_b, ca_down_w, ca_down_b,
                                      ca_up_w, ca_up_b, sr_w, st_w, ws + 12288);
    fuse_kernel<<<dim3(200, 4), 512, 0, stream>>>(RGB, T, ws + 12288, sr_b, st_b, out);
}

// Round 12
// 135.912 us; speedup vs baseline: 1.1810x; 1.0349x over previous
//
#include <hip/hip_runtime.h>
#include <hip/hip_fp16.h>
#include <cfloat>
#include <cmath>

#define HW 25600      // 160*160
#define WIDTH 160
#define NB 4
#define NC 128

typedef float f32x2 __attribute__((ext_vector_type(2)));

__device__ __forceinline__ float gelu_exact(float x) {
    return 0.5f * x * (1.f + erff(x * 0.70710678118654752f));
}
__device__ __forceinline__ float sigmoidf_(float x) {
    return 1.f / (1.f + expf(-x));
}

__device__ __forceinline__ unsigned pack_pkrtz(float a, float b) {
    return __builtin_bit_cast(unsigned, __builtin_amdgcn_cvt_pkrtz(a, b));
}
__device__ __forceinline__ __half2 u2h(unsigned u) {
    return __builtin_bit_cast(__half2, u);
}
__device__ __forceinline__ float h2sum(__half2 h) {
    return __half2float(__low2half(h)) + __half2float(__high2half(h));
}

// ---------------- K1: per-plane means + (merged) conv-weight pack ----------------
// Blocks 0..1023: per-plane means. Blocks 1024..1072: pack f16x2 weights.
__global__ __launch_bounds__(256) void mean_pack_kernel(const float* __restrict__ RGB,
                                                        const float* __restrict__ T,
                                                        const float* __restrict__ dww,
                                                        float* __restrict__ means,
                                                        unsigned* __restrict__ wpk) {
    int p = blockIdx.x;
    if (p >= 1024) {
        int i = (p - 1024) * 256 + threadIdx.x;  // 128*98 = 12544
        if (i < 128 * 98) {
            int g = i / 98; int r = i - g * 98;
            int ky = r / 14; int r2 = r - ky * 14;
            int oc = r2 / 7; int kx = r2 - oc * 7;
            int o = 2 * g + oc;
            float wa = dww[(o * 2 + 0) * 49 + ky * 7 + kx];
            float wb = dww[(o * 2 + 1) * 49 + ky * 7 + kx];
            wpk[i] = pack_pkrtz(wa, wb);
        }
        return;
    }
    const float* src = (p < 512) ? (RGB + (size_t)p * HW)
                                 : (T + (size_t)(p - 512) * HW);
    const float4* s4 = (const float4*)src;
    float s = 0.f;
    for (int i = threadIdx.x; i < HW / 4; i += 256) {
        float4 v = s4[i];
        s += (v.x + v.y) + (v.z + v.w);
    }
    for (int off = 32; off; off >>= 1) s += __shfl_down(s, off);
    __shared__ float r[4];
    if ((threadIdx.x & 63) == 0) r[threadIdx.x >> 6] = s;
    __syncthreads();
    if (threadIdx.x == 0) means[p] = (r[0] + r[1] + r[2] + r[3]) * (1.f / (float)HW);
}

// ---------------- K2: feature-pool MLP + L2-normalize, per (tau,b) ----------------
__global__ __launch_bounds__(256) void mlp_kernel(const float* __restrict__ means,
                                                  const float* __restrict__ dww,
                                                  const float* __restrict__ dwb,
                                                  const float* __restrict__ uww,
                                                  const float* __restrict__ uwb,
                                                  float* __restrict__ ynorm) {
    int tb = blockIdx.x;  // tau*4 + b
    int t = threadIdx.x;
    __shared__ float sm[128];
    __shared__ float sh[256];
    __shared__ float zz[256];
    __shared__ float r4[4];
    if (t < 128) sm[t] = means[tb * 128 + t];
    __syncthreads();
    float a = dwb[t];
    const float* wrow = dww + t * 128;
    for (int c = 0; c < 128; ++c) a += wrow[c] * sm[c];
    sh[t] = gelu_exact(a);
    __syncthreads();
    int c = t & 127, half = t >> 7;
    float z = 0.f;
    const float* urow = uww + c * 256 + half * 128;
    const float* hh = sh + half * 128;
    for (int j = 0; j < 128; ++j) z += urow[j] * hh[j];
    zz[t] = z;
    __syncthreads();
    float y = 0.f;
    if (t < 128) y = zz[t] + zz[t + 128] + uwb[t];
    float p = y * y;
    for (int off = 32; off; off >>= 1) p += __shfl_down(p, off);
    if ((t & 63) == 0) r4[t >> 6] = p;
    __syncthreads();
    float nrm = sqrtf(r4[0] + r4[1] + r4[2] + r4[3]);
    if (t < 128) ynorm[tb * 128 + t] = y / nrm;
}

// ---------------- K3: gated grouped 7x7 conv + spatial max (R11-proven, 67.5us plateau) ----------------
#define TW2 166
#define THR 22
#define NYT 10
__global__ __launch_bounds__(256, 8) void conv_max_kernel(const float* __restrict__ RGB,
                                                          const float* __restrict__ T,
                                                          const unsigned* __restrict__ wpk,
                                                          const float* __restrict__ ynorm,
                                                          float* __restrict__ part) {
    int yt = blockIdx.x;  // 0..9
    int g  = blockIdx.y;  // 0..127
    int b  = blockIdx.z;  // 0..3
    int t  = threadIdx.x;
    __shared__ unsigned tile[THR * TW2];   // 14.6 KB
    __shared__ float r0s[4], r1s[4];
    int ic0 = 2 * g;
    int c0 = ic0 & 127, c1 = (ic0 + 1) & 127;
    const float* base = (ic0 < 128) ? RGB : T;
    const float* plane0 = base + ((size_t)(b * 128 + c0)) * HW;
    const float* plane1 = base + ((size_t)(b * 128 + c1)) * HW;
    int i0 = b * 128 + c0, i1 = b * 128 + c1;
    int j0 = i0 & 3, k0 = i0 >> 2, j1 = i1 & 3, k1 = i1 >> 2;
    float gate0 = sigmoidf_(128.f * ynorm[j0 * 128 + j0] * ynorm[512 + j0 * 128 + k0]);
    float gate1 = sigmoidf_(128.f * ynorm[j1 * 128 + j1] * ynorm[512 + j1 * 128 + k1]);
    int y0 = yt * 16 - 3;
    for (int e = t; e < THR * TW2; e += 256) {
        int row = e / TW2;
        int col = e - row * TW2;
        int gy = y0 + row, gx = col - 3;
        float v0 = 0.f, v1 = 0.f;
        if (gy >= 0 && gy < 160 && gx >= 0 && gx < 160) {
            int off = gy * WIDTH + gx;
            v0 = plane0[off] * gate0;
            v1 = plane1[off] * gate1;
        }
        tile[e] = pack_pkrtz(v0, v1);
    }
    __syncthreads();
    int xs = (t & 15) * 10;     // 40 B aligned -> uint2 ok
    int ys = t >> 4;            // 0..15
    __half2 A0 = u2h(0u), A1 = u2h(0u), A2 = u2h(0u), A3 = u2h(0u), A4 = u2h(0u);
    __half2 A5 = u2h(0u), A6 = u2h(0u), A7 = u2h(0u), A8 = u2h(0u), A9 = u2h(0u);
    __half2 B0 = u2h(0u), B1 = u2h(0u), B2 = u2h(0u), B3 = u2h(0u), B4 = u2h(0u);
    __half2 B5 = u2h(0u), B6 = u2h(0u), B7 = u2h(0u), B8 = u2h(0u), B9 = u2h(0u);
    const unsigned* wgp = wpk + g * 98;   // block-uniform -> scalar loads
    #pragma unroll 2
    for (int ky = 0; ky < 7; ++ky) {
        unsigned wk[14];
        #pragma unroll
        for (int j = 0; j < 14; ++j) wk[j] = wgp[ky * 14 + j];
        const uint2* tr2 = (const uint2*)(tile + (ys + ky) * TW2 + xs);
        unsigned win[16];
        #pragma unroll
        for (int j = 0; j < 8; ++j) {
            uint2 p = tr2[j];
            win[2 * j] = p.x;
            win[2 * j + 1] = p.y;
        }
        #pragma unroll
        for (int kx = 0; kx < 7; ++kx) {
            __half2 w0 = u2h(wk[kx]);
            __half2 w1 = u2h(wk[7 + kx]);
            __half2 v;
            v = u2h(win[kx + 0]); A0 = __hfma2(w0, v, A0); B0 = __hfma2(w1, v, B0);
            v = u2h(win[kx + 1]); A1 = __hfma2(w0, v, A1); B1 = __hfma2(w1, v, B1);
            v = u2h(win[kx + 2]); A2 = __hfma2(w0, v, A2); B2 = __hfma2(w1, v, B2);
            v = u2h(win[kx + 3]); A3 = __hfma2(w0, v, A3); B3 = __hfma2(w1, v, B3);
            v = u2h(win[kx + 4]); A4 = __hfma2(w0, v, A4); B4 = __hfma2(w1, v, B4);
            v = u2h(win[kx + 5]); A5 = __hfma2(w0, v, A5); B5 = __hfma2(w1, v, B5);
            v = u2h(win[kx + 6]); A6 = __hfma2(w0, v, A6); B6 = __hfma2(w1, v, B6);
            v = u2h(win[kx + 7]); A7 = __hfma2(w0, v, A7); B7 = __hfma2(w1, v, B7);
            v = u2h(win[kx + 8]); A8 = __hfma2(w0, v, A8); B8 = __hfma2(w1, v, B8);
            v = u2h(win[kx + 9]); A9 = __hfma2(w0, v, A9); B9 = __hfma2(w1, v, B9);
        }
    }
    float m0 = fmaxf(fmaxf(fmaxf(h2sum(A0), h2sum(A1)), fmaxf(h2sum(A2), h2sum(A3))),
                     fmaxf(fmaxf(h2sum(A4), h2sum(A5)),
                           fmaxf(fmaxf(h2sum(A6), h2sum(A7)), fmaxf(h2sum(A8), h2sum(A9)))));
    float m1 = fmaxf(fmaxf(fmaxf(h2sum(B0), h2sum(B1)), fmaxf(h2sum(B2), h2sum(B3))),
                     fmaxf(fmaxf(h2sum(B4), h2sum(B5)),
                           fmaxf(fmaxf(h2sum(B6), h2sum(B7)), fmaxf(h2sum(B8), h2sum(B9)))));
    for (int off = 32; off; off >>= 1) {
        m0 = fmaxf(m0, __shfl_down(m0, off));
        m1 = fmaxf(m1, __shfl_down(m1, off));
    }
    if ((t & 63) == 0) { r0s[t >> 6] = m0; r1s[t >> 6] = m1; }
    __syncthreads();
    if (t == 0) {
        m0 = fmaxf(fmaxf(r0s[0], r0s[1]), fmaxf(r0s[2], r0s[3]));
        m1 = fmaxf(fmaxf(r1s[0], r1s[1]), fmaxf(r1s[2], r1s[3]));
        int bb = ((b * 128 + g) * NYT + yt) * 2;
        part[bb] = m0;
        part[bb + 1] = m1;
    }
}

// ---------------- K4: max-reduce + channel-att MLP -> per-channel coefficients ----------------
__global__ __launch_bounds__(256) void att_kernel(const float* __restrict__ ynorm,
                                                  const float* __restrict__ part,
                                                  const float* __restrict__ dwb,
                                                  const float* __restrict__ cdw,
                                                  const float* __restrict__ cdb,
                                                  const float* __restrict__ cuw,
                                                  const float* __restrict__ cub,
                                                  const float* __restrict__ srw,
                                                  const float* __restrict__ stw,
                                                  float* __restrict__ coefs) {
    int t = threadIdx.x;
    __shared__ float scg[512];
    __shared__ float smax[1024];
    __shared__ float sh2[64];
    __shared__ float sfg[1024];
    for (int idx = t; idx < 512; idx += 256) {
        int kk = idx >> 2, j = idx & 3;
        scg[idx] = sigmoidf_(128.f * ynorm[j * 128 + j] * ynorm[512 + j * 128 + kk]);
    }
    for (int idx = t; idx < 1024; idx += 256) {
        int b = idx >> 8, o = idx & 255;
        int gg = o >> 1, oc = o & 1;
        const float* pp = part + ((b * 128 + gg) * NYT) * 2 + oc;
        float m = pp[0];
        #pragma unroll
        for (int yt = 1; yt < NYT; ++yt) m = fmaxf(m, pp[yt * 2]);
        smax[idx] = m + dwb[o];
    }
    __syncthreads();
    if (t < 64) {
        int b = t >> 4, j = t & 15;
        float a = cdb[j];
        const float* wrow = cdw + j * 256;
        const float* mx = smax + b * 256;
        for (int o = 0; o < 256; ++o) a += wrow[o] * mx[o];
        sh2[t] = gelu_exact(a);
    }
    __syncthreads();
    for (int idx = t; idx < 1024; idx += 256) {
        int b = idx >> 8, o = idx & 255;
        float z = cub[o];
        const float* ur = cuw + o * 16;
        const float* hh = sh2 + b * 16;
        #pragma unroll
        for (int j = 0; j < 16; ++j) z += ur[j] * hh[j];
        sfg[idx] = sigmoidf_(z);
    }
    __syncthreads();
    for (int idx = t; idx < 512; idx += 256) {
        int b = idx >> 7, c = idx & 127;
        float cgv = scg[idx];
        float ar = cgv * sfg[b * 256 + c] + 1.f - cgv;
        float at = cgv * sfg[b * 256 + 128 + c] + 1.f - cgv;
        coefs[idx] = ar;
        coefs[512 + idx] = at;
        coefs[1024 + idx] = ar * srw[c];
        coefs[1536 + idx] = at * stw[c];
    }
}

// ---------------- K5: spatial-att fuse, single pass, float2, 8 warps x 16ch ----------------
// R12 fix: launch_bounds(512,4) -> 2 blocks/CU (16 waves), vs (512,2) which
// capped at 1 block/CU (8 waves) and throttled this memory-bound kernel.
__global__ __launch_bounds__(512, 4) void fuse_kernel(const float* __restrict__ RGB,
                                                      const float* __restrict__ T,
                                                      const float* __restrict__ coefs,
                                                      const float* __restrict__ srb,
                                                      const float* __restrict__ stb,
                                                      float* __restrict__ out) {
    int b = blockIdx.y;
    int t = threadIdx.x;
    int w = t >> 6, lane = t & 63;
    int pix = blockIdx.x * 128 + lane * 2;
    __shared__ float sco[4][128];
    if (t < 512) {
        int a = t >> 7, c = t & 127;
        sco[a][c] = coefs[a * 512 + b * 128 + c];
    }
    __syncthreads();
    const float* rp = RGB + (size_t)b * NC * HW;
    const float* tp = T + (size_t)b * NC * HW;
    f32x2 rv[16], tv[16];
    f32x2 df; df.x = 0.f; df.y = 0.f;
    #pragma unroll
    for (int ci = 0; ci < 16; ++ci) {
        int c = w * 16 + ci;
        size_t off = (size_t)c * HW + pix;
        rv[ci] = *(const f32x2*)(rp + off);
        tv[ci] = *(const f32x2*)(tp + off);
        float wrc = sco[2][c], wtc = sco[3][c];
        df.x += rv[ci].x * wrc - tv[ci].x * wtc;
        df.y += rv[ci].y * wrc - tv[ci].y * wtc;
    }
    __shared__ f32x2 sdf[8][64];
    sdf[w][lane] = df;
    __syncthreads();
    float sx = srb[0] - stb[0], sy = sx;
    #pragma unroll
    for (int ww = 0; ww < 8; ++ww) {
        f32x2 d = sdf[ww][lane];
        sx += d.x;
        sy += d.y;
    }
    float ax = sigmoidf_(sx), ay = sigmoidf_(sy);
    float* outR = out + (size_t)b * NC * HW;
    float* outT = out + (size_t)NB * NC * HW + (size_t)b * NC * HW;
    #pragma unroll
    for (int ci = 0; ci < 16; ++ci) {
        int c = w * 16 + ci;
        size_t off = (size_t)c * HW + pix;
        float arc = sco[0][c], atc = sco[1][c];
        f32x2 o1, o2;
        o1.x = rv[ci].x * arc * ax;         o1.y = rv[ci].y * arc * ay;
        o2.x = tv[ci].x * atc * (1.f - ax); o2.y = tv[ci].y * atc * (1.f - ay);
        __builtin_nontemporal_store(o1, (f32x2*)(outR + off));
        __builtin_nontemporal_store(o2, (f32x2*)(outT + off));
    }
}

extern "C" void kernel_launch(void* const* d_in, const int* in_sizes, int n_in,
                              void* d_out, int out_size, void* d_ws, size_t ws_size,
                              hipStream_t stream) {
    const float* RGB       = (const float*)d_in[0];
    const float* T         = (const float*)d_in[1];
    const float* fp_down_w = (const float*)d_in[2];
    const float* fp_down_b = (const float*)d_in[3];
    const float* fp_up_w   = (const float*)d_in[4];
    const float* fp_up_b   = (const float*)d_in[5];
    const float* dw_w      = (const float*)d_in[6];
    const float* dw_b      = (const float*)d_in[7];
    const float* ca_down_w = (const float*)d_in[8];
    const float* ca_down_b = (const float*)d_in[9];
    const float* ca_up_w   = (const float*)d_in[10];
    const float* ca_up_b   = (const float*)d_in[11];
    const float* sr_w      = (const float*)d_in[12];
    const float* sr_b      = (const float*)d_in[13];
    const float* st_w      = (const float*)d_in[14];
    const float* st_b      = (const float*)d_in[15];
    float* out = (float*)d_out;
    float* ws  = (float*)d_ws;

    // ws float layout (R8-proven footprint):
    //   [0,1024)        means (tau*512 + b*128 + c)
    //   [1024,2048)     ynorm
    //   [2048,12288)    conv partial maxes: ((b*128+g)*10+yt)*2 + oc
    //   [12288,14336)   coefs: alpha_r | alpha_t | wr | wt  (each 512)
    //   [14336,26880)   wpk: packed f16x2 conv weights [g][ky][oc][kx]
    unsigned* wpk = (unsigned*)(ws + 14336);
    mean_pack_kernel<<<1073, 256, 0, stream>>>(RGB, T, dw_w, ws, wpk);
    mlp_kernel<<<8, 256, 0, stream>>>(ws, fp_down_w, fp_down_b, fp_up_w, fp_up_b, ws + 1024);
    conv_max_kernel<<<dim3(NYT, 128, 4), 256, 0, stream>>>(RGB, T, wpk, ws + 1024, ws + 2048);
    att_kernel<<<1, 256, 0, stream>>>(ws + 1024, ws + 2048, dw_b, ca_down_w, ca_down_b,
                                      ca_up_w, ca_up_b, sr_w, st_w, ws + 12288);
    fuse_kernel<<<dim3(200, 4), 512, 0, stream>>>(RGB, T, ws + 12288, sr_b, st_b, out);
}

// Round 13
// 134.933 us; speedup vs baseline: 1.1896x; 1.0073x over previous
//
#include <hip/hip_runtime.h>
#include <hip/hip_fp16.h>
#include <cfloat>
#include <cmath>

#define HW 25600      // 160*160
#define WIDTH 160
#define NB 4
#define NC 128

typedef float f32x2 __attribute__((ext_vector_type(2)));

__device__ __forceinline__ float gelu_exact(float x) {
    return 0.5f * x * (1.f + erff(x * 0.70710678118654752f));
}
__device__ __forceinline__ float sigmoidf_(float x) {
    return 1.f / (1.f + expf(-x));
}

__device__ __forceinline__ unsigned pack_pkrtz(float a, float b) {
    return __builtin_bit_cast(unsigned, __builtin_amdgcn_cvt_pkrtz(a, b));
}
__device__ __forceinline__ __half2 u2h(unsigned u) {
    return __builtin_bit_cast(__half2, u);
}
__device__ __forceinline__ float h2sum(__half2 h) {
    return __half2float(__low2half(h)) + __half2float(__high2half(h));
}

// ---------------- K1: per-plane means + (merged) conv-weight pack ----------------
__global__ __launch_bounds__(256) void mean_pack_kernel(const float* __restrict__ RGB,
                                                        const float* __restrict__ T,
                                                        const float* __restrict__ dww,
                                                        float* __restrict__ means,
                                                        unsigned* __restrict__ wpk) {
    int p = blockIdx.x;
    if (p >= 1024) {
        int i = (p - 1024) * 256 + threadIdx.x;  // 128*98 = 12544
        if (i < 128 * 98) {
            int g = i / 98; int r = i - g * 98;
            int ky = r / 14; int r2 = r - ky * 14;
            int oc = r2 / 7; int kx = r2 - oc * 7;
            int o = 2 * g + oc;
            float wa = dww[(o * 2 + 0) * 49 + ky * 7 + kx];
            float wb = dww[(o * 2 + 1) * 49 + ky * 7 + kx];
            wpk[i] = pack_pkrtz(wa, wb);
        }
        return;
    }
    const float* src = (p < 512) ? (RGB + (size_t)p * HW)
                                 : (T + (size_t)(p - 512) * HW);
    const float4* s4 = (const float4*)src;
    float s = 0.f;
    for (int i = threadIdx.x; i < HW / 4; i += 256) {
        float4 v = s4[i];
        s += (v.x + v.y) + (v.z + v.w);
    }
    for (int off = 32; off; off >>= 1) s += __shfl_down(s, off);
    __shared__ float r[4];
    if ((threadIdx.x & 63) == 0) r[threadIdx.x >> 6] = s;
    __syncthreads();
    if (threadIdx.x == 0) means[p] = (r[0] + r[1] + r[2] + r[3]) * (1.f / (float)HW);
}

// ---------------- K2: feature-pool MLP + L2-normalize, per (tau,b) ----------------
__global__ __launch_bounds__(256) void mlp_kernel(const float* __restrict__ means,
                                                  const float* __restrict__ dww,
                                                  const float* __restrict__ dwb,
                                                  const float* __restrict__ uww,
                                                  const float* __restrict__ uwb,
                                                  float* __restrict__ ynorm) {
    int tb = blockIdx.x;  // tau*4 + b
    int t = threadIdx.x;
    __shared__ float sm[128];
    __shared__ float sh[256];
    __shared__ float zz[256];
    __shared__ float r4[4];
    if (t < 128) sm[t] = means[tb * 128 + t];
    __syncthreads();
    float a = dwb[t];
    const float* wrow = dww + t * 128;
    for (int c = 0; c < 128; ++c) a += wrow[c] * sm[c];
    sh[t] = gelu_exact(a);
    __syncthreads();
    int c = t & 127, half = t >> 7;
    float z = 0.f;
    const float* urow = uww + c * 256 + half * 128;
    const float* hh = sh + half * 128;
    for (int j = 0; j < 128; ++j) z += urow[j] * hh[j];
    zz[t] = z;
    __syncthreads();
    float y = 0.f;
    if (t < 128) y = zz[t] + zz[t + 128] + uwb[t];
    float p = y * y;
    for (int off = 32; off; off >>= 1) p += __shfl_down(p, off);
    if ((t & 63) == 0) r4[t >> 6] = p;
    __syncthreads();
    float nrm = sqrtf(r4[0] + r4[1] + r4[2] + r4[3]);
    if (t < 128) ynorm[tb * 128 + t] = y / nrm;
}

// ---------------- K3: gated grouped 7x7 conv + spatial max ----------------
// R13: XCD-chunked block swizzle (all 10 yt-blocks of a (b,g) pair land on one
// XCD -> planes stay in that XCD's L2) + full ky unroll (hoistable ds_reads).
#define TW2 166
#define THR 22
#define NYT 10
__global__ __launch_bounds__(256, 8) void conv_max_kernel(const float* __restrict__ RGB,
                                                          const float* __restrict__ T,
                                                          const unsigned* __restrict__ wpk,
                                                          const float* __restrict__ ynorm,
                                                          float* __restrict__ part) {
    // bijective XCD swizzle: 5120 blocks, 5120 % 8 == 0
    int orig = blockIdx.x;
    int wg = (orig & 7) * 640 + (orig >> 3);
    int b  = wg / 1280;
    int rr = wg - b * 1280;
    int g  = rr / NYT;
    int yt = rr - g * NYT;
    int t  = threadIdx.x;
    __shared__ unsigned tile[THR * TW2];   // 14.6 KB
    __shared__ float r0s[4], r1s[4];
    int ic0 = 2 * g;
    int c0 = ic0 & 127, c1 = (ic0 + 1) & 127;
    const float* base = (ic0 < 128) ? RGB : T;
    const float* plane0 = base + ((size_t)(b * 128 + c0)) * HW;
    const float* plane1 = base + ((size_t)(b * 128 + c1)) * HW;
    int i0 = b * 128 + c0, i1 = b * 128 + c1;
    int j0 = i0 & 3, k0 = i0 >> 2, j1 = i1 & 3, k1 = i1 >> 2;
    float gate0 = sigmoidf_(128.f * ynorm[j0 * 128 + j0] * ynorm[512 + j0 * 128 + k0]);
    float gate1 = sigmoidf_(128.f * ynorm[j1 * 128 + j1] * ynorm[512 + j1 * 128 + k1]);
    int y0 = yt * 16 - 3;
    for (int e = t; e < THR * TW2; e += 256) {
        int row = e / TW2;
        int col = e - row * TW2;
        int gy = y0 + row, gx = col - 3;
        float v0 = 0.f, v1 = 0.f;
        if (gy >= 0 && gy < 160 && gx >= 0 && gx < 160) {
            int off = gy * WIDTH + gx;
            v0 = plane0[off] * gate0;
            v1 = plane1[off] * gate1;
        }
        tile[e] = pack_pkrtz(v0, v1);
    }
    __syncthreads();
    int xs = (t & 15) * 10;     // 40 B aligned -> uint2 ok
    int ys = t >> 4;            // 0..15
    __half2 A0 = u2h(0u), A1 = u2h(0u), A2 = u2h(0u), A3 = u2h(0u), A4 = u2h(0u);
    __half2 A5 = u2h(0u), A6 = u2h(0u), A7 = u2h(0u), A8 = u2h(0u), A9 = u2h(0u);
    __half2 B0 = u2h(0u), B1 = u2h(0u), B2 = u2h(0u), B3 = u2h(0u), B4 = u2h(0u);
    __half2 B5 = u2h(0u), B6 = u2h(0u), B7 = u2h(0u), B8 = u2h(0u), B9 = u2h(0u);
    const unsigned* wgp = wpk + g * 98;   // block-uniform -> scalar loads
    #pragma unroll
    for (int ky = 0; ky < 7; ++ky) {
        unsigned wk[14];
        #pragma unroll
        for (int j = 0; j < 14; ++j) wk[j] = wgp[ky * 14 + j];
        const uint2* tr2 = (const uint2*)(tile + (ys + ky) * TW2 + xs);
        unsigned win[16];
        #pragma unroll
        for (int j = 0; j < 8; ++j) {
            uint2 p = tr2[j];
            win[2 * j] = p.x;
            win[2 * j + 1] = p.y;
        }
        #pragma unroll
        for (int kx = 0; kx < 7; ++kx) {
            __half2 w0 = u2h(wk[kx]);
            __half2 w1 = u2h(wk[7 + kx]);
            __half2 v;
            v = u2h(win[kx + 0]); A0 = __hfma2(w0, v, A0); B0 = __hfma2(w1, v, B0);
            v = u2h(win[kx + 1]); A1 = __hfma2(w0, v, A1); B1 = __hfma2(w1, v, B1);
            v = u2h(win[kx + 2]); A2 = __hfma2(w0, v, A2); B2 = __hfma2(w1, v, B2);
            v = u2h(win[kx + 3]); A3 = __hfma2(w0, v, A3); B3 = __hfma2(w1, v, B3);
            v = u2h(win[kx + 4]); A4 = __hfma2(w0, v, A4); B4 = __hfma2(w1, v, B4);
            v = u2h(win[kx + 5]); A5 = __hfma2(w0, v, A5); B5 = __hfma2(w1, v, B5);
            v = u2h(win[kx + 6]); A6 = __hfma2(w0, v, A6); B6 = __hfma2(w1, v, B6);
            v = u2h(win[kx + 7]); A7 = __hfma2(w0, v, A7); B7 = __hfma2(w1, v, B7);
            v = u2h(win[kx + 8]); A8 = __hfma2(w0, v, A8); B8 = __hfma2(w1, v, B8);
            v = u2h(win[kx + 9]); A9 = __hfma2(w0, v, A9); B9 = __hfma2(w1, v, B9);
        }
    }
    float m0 = fmaxf(fmaxf(fmaxf(h2sum(A0), h2sum(A1)), fmaxf(h2sum(A2), h2sum(A3))),
                     fmaxf(fmaxf(h2sum(A4), h2sum(A5)),
                           fmaxf(fmaxf(h2sum(A6), h2sum(A7)), fmaxf(h2sum(A8), h2sum(A9)))));
    float m1 = fmaxf(fmaxf(fmaxf(h2sum(B0), h2sum(B1)), fmaxf(h2sum(B2), h2sum(B3))),
                     fmaxf(fmaxf(h2sum(B4), h2sum(B5)),
                           fmaxf(fmaxf(h2sum(B6), h2sum(B7)), fmaxf(h2sum(B8), h2sum(B9)))));
    for (int off = 32; off; off >>= 1) {
        m0 = fmaxf(m0, __shfl_down(m0, off));
        m1 = fmaxf(m1, __shfl_down(m1, off));
    }
    if ((t & 63) == 0) { r0s[t >> 6] = m0; r1s[t >> 6] = m1; }
    __syncthreads();
    if (t == 0) {
        m0 = fmaxf(fmaxf(r0s[0], r0s[1]), fmaxf(r0s[2], r0s[3]));
        m1 = fmaxf(fmaxf(r1s[0], r1s[1]), fmaxf(r1s[2], r1s[3]));
        int bb = ((b * 128 + g) * NYT + yt) * 2;
        part[bb] = m0;
        part[bb + 1] = m1;
    }
}

// ---------------- K4: max-reduce + channel-att MLP -> per-channel coefficients ----------------
__global__ __launch_bounds__(256) void att_kernel(const float* __restrict__ ynorm,
                                                  const float* __restrict__ part,
                                                  const float* __restrict__ dwb,
                                                  const float* __restrict__ cdw,
                                                  const float* __restrict__ cdb,
                                                  const float* __restrict__ cuw,
                                                  const float* __restrict__ cub,
                                                  const float* __restrict__ srw,
                                                  const float* __restrict__ stw,
                                                  float* __restrict__ coefs) {
    int t = threadIdx.x;
    __shared__ float scg[512];
    __shared__ float smax[1024];
    __shared__ float sh2[64];
    __shared__ float sfg[1024];
    for (int idx = t; idx < 512; idx += 256) {
        int kk = idx >> 2, j = idx & 3;
        scg[idx] = sigmoidf_(128.f * ynorm[j * 128 + j] * ynorm[512 + j * 128 + kk]);
    }
    for (int idx = t; idx < 1024; idx += 256) {
        int b = idx >> 8, o = idx & 255;
        int gg = o >> 1, oc = o & 1;
        const float* pp = part + ((b * 128 + gg) * NYT) * 2 + oc;
        float m = pp[0];
        #pragma unroll
        for (int yt = 1; yt < NYT; ++yt) m = fmaxf(m, pp[yt * 2]);
        smax[idx] = m + dwb[o];
    }
    __syncthreads();
    if (t < 64) {
        int b = t >> 4, j = t & 15;
        float a = cdb[j];
        const float* wrow = cdw + j * 256;
        const float* mx = smax + b * 256;
        for (int o = 0; o < 256; ++o) a += wrow[o] * mx[o];
        sh2[t] = gelu_exact(a);
    }
    __syncthreads();
    for (int idx = t; idx < 1024; idx += 256) {
        int b = idx >> 8, o = idx & 255;
        float z = cub[o];
        const float* ur = cuw + o * 16;
        const float* hh = sh2 + b * 16;
        #pragma unroll
        for (int j = 0; j < 16; ++j) z += ur[j] * hh[j];
        sfg[idx] = sigmoidf_(z);
    }
    __syncthreads();
    for (int idx = t; idx < 512; idx += 256) {
        int b = idx >> 7, c = idx & 127;
        float cgv = scg[idx];
        float ar = cgv * sfg[b * 256 + c] + 1.f - cgv;
        float at = cgv * sfg[b * 256 + 128 + c] + 1.f - cgv;
        coefs[idx] = ar;
        coefs[512 + idx] = at;
        coefs[1024 + idx] = ar * srw[c];
        coefs[1536 + idx] = at * stw[c];
    }
}

// ---------------- K5: spatial-att fuse, single pass, float2, 8 warps x 16ch ----------------
__global__ __launch_bounds__(512, 4) void fuse_kernel(const float* __restrict__ RGB,
                                                      const float* __restrict__ T,
                                                      const float* __restrict__ coefs,
                                                      const float* __restrict__ srb,
                                                      const float* __restrict__ stb,
                                                      float* __restrict__ out) {
    int b = blockIdx.y;
    int t = threadIdx.x;
    int w = t >> 6, lane = t & 63;
    int pix = blockIdx.x * 128 + lane * 2;
    __shared__ float sco[4][128];
    if (t < 512) {
        int a = t >> 7, c = t & 127;
        sco[a][c] = coefs[a * 512 + b * 128 + c];
    }
    __syncthreads();
    const float* rp = RGB + (size_t)b * NC * HW;
    const float* tp = T + (size_t)b * NC * HW;
    f32x2 rv[16], tv[16];
    f32x2 df; df.x = 0.f; df.y = 0.f;
    #pragma unroll
    for (int ci = 0; ci < 16; ++ci) {
        int c = w * 16 + ci;
        size_t off = (size_t)c * HW + pix;
        rv[ci] = *(const f32x2*)(rp + off);
        tv[ci] = *(const f32x2*)(tp + off);
        float wrc = sco[2][c], wtc = sco[3][c];
        df.x += rv[ci].x * wrc - tv[ci].x * wtc;
        df.y += rv[ci].y * wrc - tv[ci].y * wtc;
    }
    __shared__ f32x2 sdf[8][64];
    sdf[w][lane] = df;
    __syncthreads();
    float sx = srb[0] - stb[0], sy = sx;
    #pragma unroll
    for (int ww = 0; ww < 8; ++ww) {
        f32x2 d = sdf[ww][lane];
        sx += d.x;
        sy += d.y;
    }
    float ax = sigmoidf_(sx), ay = sigmoidf_(sy);
    float* outR = out + (size_t)b * NC * HW;
    float* outT = out + (size_t)NB * NC * HW + (size_t)b * NC * HW;
    #pragma unroll
    for (int ci = 0; ci < 16; ++ci) {
        int c = w * 16 + ci;
        size_t off = (size_t)c * HW + pix;
        float arc = sco[0][c], atc = sco[1][c];
        f32x2 o1, o2;
        o1.x = rv[ci].x * arc * ax;         o1.y = rv[ci].y * arc * ay;
        o2.x = tv[ci].x * atc * (1.f - ax); o2.y = tv[ci].y * atc * (1.f - ay);
        __builtin_nontemporal_store(o1, (f32x2*)(outR + off));
        __builtin_nontemporal_store(o2, (f32x2*)(outT + off));
    }
}

extern "C" void kernel_launch(void* const* d_in, const int* in_sizes, int n_in,
                              void* d_out, int out_size, void* d_ws, size_t ws_size,
                              hipStream_t stream) {
    const float* RGB       = (const float*)d_in[0];
    const float* T         = (const float*)d_in[1];
    const float* fp_down_w = (const float*)d_in[2];
    const float* fp_down_b = (const float*)d_in[3];
    const float* fp_up_w   = (const float*)d_in[4];
    const float* fp_up_b   = (const float*)d_in[5];
    const float* dw_w      = (const float*)d_in[6];
    const float* dw_b      = (const float*)d_in[7];
    const float* ca_down_w = (const float*)d_in[8];
    const float* ca_down_b = (const float*)d_in[9];
    const float* ca_up_w   = (const float*)d_in[10];
    const float* ca_up_b   = (const float*)d_in[11];
    const float* sr_w      = (const float*)d_in[12];
    const float* sr_b      = (const float*)d_in[13];
    const float* st_w      = (const float*)d_in[14];
    const float* st_b      = (const float*)d_in[15];
    float* out = (float*)d_out;
    float* ws  = (float*)d_ws;

    // ws float layout (proven footprint):
    //   [0,1024)        means
    //   [1024,2048)     ynorm
    //   [2048,12288)    conv partial maxes
    //   [12288,14336)   coefs: alpha_r | alpha_t | wr | wt
    //   [14336,26880)   wpk: packed f16x2 conv weights [g][ky][oc][kx]
    unsigned* wpk = (unsigned*)(ws + 14336);
    mean_pack_kernel<<<1073, 256, 0, stream>>>(RGB, T, dw_w, ws, wpk);
    mlp_kernel<<<8, 256, 0, stream>>>(ws, fp_down_w, fp_down_b, fp_up_w, fp_up_b, ws + 1024);
    conv_max_kernel<<<5120, 256, 0, stream>>>(RGB, T, wpk, ws + 1024, ws + 2048);
    att_kernel<<<1, 256, 0, stream>>>(ws + 1024, ws + 2048, dw_b, ca_down_w, ca_down_b,
                                      ca_up_w, ca_up_b, sr_w, st_w, ws + 12288);
    fuse_kernel<<<dim3(200, 4), 512, 0, stream>>>(RGB, T, ws + 12288, sr_b, st_b, out);
}